// Round 6
// baseline (6524.500 us; speedup 1.0000x reference)
//
#include <hip/hip_runtime.h>
#include <math.h>

typedef float fv4 __attribute__((ext_vector_type(4)));

#define NSTEP 20
#define HD 512
#define QD 256
#define VOC 128
#define RB 8          // rows per block
#define TPB 256       // 4-wave blocks; each thread owns units tid and tid+256
#define NU 2          // hidden units per thread

// ws layout (float offsets)
#define WG_OFF   0          // [kb=128][u=512][g=4][ki=4] = 1048576 floats (4 MB)
#define WIH_OFF  1048576    // [x=128][u=512][g=4]        = 262144
#define WIN_OFF  1310720    // [kb=64][u=512][ki=4]       = 131072
#define WOUT_OFF 1441792    // [kb=128][v=128][ki=4]      = 65536

// numpy-style f32 elementwise ops (verbatim from the passing round-5 kernel).
__device__ __forceinline__ float sig_np(float x) {
  float t = (float)exp(-(double)x);              // corr-rounded f32 exp
  return __fdiv_rn(1.0f, __fadd_rn(1.0f, t));
}
__device__ __forceinline__ float tanh_np(float x) {
  return (float)tanh((double)x);
}

// Repack weights into lane-contiguous layouts (pure data movement; the values
// feeding each FMA chain are unchanged, so the trajectory stays bit-identical).
// Wg[kb][u][g][ki]: a thread's 4 gate-vectors per unit are 64 B contiguous.
// Wih[x][u][g]: per-(row,unit) gate gather is a single dwordx4.
__global__ void repack_kernel(const float* __restrict__ w_in,
                              const float* __restrict__ w_ih,
                              const float* __restrict__ w_hh,
                              const float* __restrict__ w_out,
                              float* __restrict__ ws) {
  int t = blockIdx.x * blockDim.x + threadIdx.x;
  {
    // Wg[kb][u][g][ki] = w_hh[(g*512+u)*512 + kb*4+ki]
    int ki = t & 3, g = (t >> 2) & 3, u = (t >> 4) & 511, kb = t >> 13;
    ws[WG_OFF + t] = w_hh[(size_t)(g * HD + u) * HD + kb * 4 + ki];
  }
  if (t < 262144) {
    // Wih[x][u][g] = w_ih[(g*512+u)*128 + x]
    int g = t & 3, u = (t >> 2) & 511, x = t >> 11;
    ws[WIH_OFF + t] = w_ih[(size_t)(g * HD + u) * VOC + x];
  }
  if (t < 131072) {
    // Win[kb][u][ki] = w_in[u*256 + kb*4+ki]
    int ki = t & 3, u = (t >> 2) & 511, kb = t >> 11;
    ws[WIN_OFF + t] = w_in[(size_t)u * QD + kb * 4 + ki];
  }
  if (t < 65536) {
    // Wout[kb][v][ki] = w_out[v*512 + kb*4+ki]
    int ki = t & 3, v = (t >> 2) & 127, kb = t >> 9;
    ws[WOUT_OFF + t] = w_out[(size_t)v * HD + kb * 4 + ki];
  }
}

// Persistent LSTM decoder. Restructured block shape vs R1: TPB=256 / RB=8 /
// 2 hidden units per thread. Per-thread work per kb is identical to R1
// (272 FMA), total waves identical; what changes:
//  - 4-wave barriers instead of 8-wave (half the sync scope),
//  - ds_read per kb halved (8 rows),
//  - register NEED ~150 with no hand-built prefetch arrays: with the
//    (256,2) cap at 256 VGPR the compiler can software-pipeline the weight
//    stream itself; if it pins 128 anyway it degrades to R1-like code
//    instead of spilling (R3/R4 lesson: never force registers via arrays).
// Every (row,unit) FMA chain (kb ascending, ki innermost), every activation
// op, and the first-max argmax are bit-identical to the verified trajectory.
__global__ __launch_bounds__(TPB, 2)
void decoder_fast(const float* __restrict__ quant,
                  const float* __restrict__ b_in,
                  const float* __restrict__ b_ih,
                  const float* __restrict__ b_hh,
                  const float* __restrict__ b_out,
                  const float* __restrict__ ws,
                  float* __restrict__ out) {
  __shared__ __align__(16) float hLDS[RB * HD];   // 16 KB: quant (prologue), then h
  __shared__ float2 cand[RB][2];                  // per-row wave-pair argmax

  const int tid  = threadIdx.x;            // 0..255
  const int u    = tid;                    // hidden unit 1
  const int u2   = tid + TPB;              // hidden unit 2
  const int row0 = blockIdx.x * RB;
  const int v    = tid & (VOC - 1);        // logit class owned by this thread
  const int rqs  = (tid >> 7) << 2;        // first logit row of this 128-thread group (0 or 4)
  const int wpar = (tid >> 6) & 1;         // wave parity within the group

  const fv4* Wg4   = (const fv4*)(ws + WG_OFF);
  const float* Wih = ws + WIH_OFF;
  const fv4* Win4  = (const fv4*)(ws + WIN_OFF);
  const fv4* Wout4 = (const fv4*)(ws + WOUT_OFF);
  const fv4* hLDS4 = (const fv4*)hLDS;

  // ---- stage quant rows into hLDS (RB*QD = 2048 floats = 512 fv4), coalesced
  {
    const fv4* src = (const fv4*)(quant + (size_t)row0 * QD);
    fv4* dst = (fv4*)hLDS;
    dst[tid]       = src[tid];
    dst[tid + TPB] = src[tid + TPB];
  }
  __syncthreads();

  // ---- h0 = quant @ w_in.T + b_in (exact chains, 2 units/thread)
  float a0[RB][NU];
  {
    const fv4* q4 = (const fv4*)hLDS;
#pragma unroll
    for (int r = 0; r < RB; ++r)
#pragma unroll
      for (int n = 0; n < NU; ++n) a0[r][n] = 0.0f;
    for (int kb = 0; kb < QD / 4; ++kb) {
      fv4 w1 = Win4[kb * 512 + u];
      fv4 w2 = Win4[kb * 512 + u2];
#pragma unroll
      for (int r = 0; r < RB; ++r) {
        fv4 qv = q4[r * 64 + kb];
        a0[r][0] = __builtin_fmaf(w1[0], qv[0], a0[r][0]);
        a0[r][0] = __builtin_fmaf(w1[1], qv[1], a0[r][0]);
        a0[r][0] = __builtin_fmaf(w1[2], qv[2], a0[r][0]);
        a0[r][0] = __builtin_fmaf(w1[3], qv[3], a0[r][0]);
        a0[r][1] = __builtin_fmaf(w2[0], qv[0], a0[r][1]);
        a0[r][1] = __builtin_fmaf(w2[1], qv[1], a0[r][1]);
        a0[r][1] = __builtin_fmaf(w2[2], qv[2], a0[r][1]);
        a0[r][1] = __builtin_fmaf(w2[3], qv[3], a0[r][1]);
      }
    }
  }
  const float binu1 = b_in[u], binu2 = b_in[u2];
  __syncthreads();                     // all quant reads done
#pragma unroll
  for (int r = 0; r < RB; ++r) {
    hLDS[r * HD + u]  = __fadd_rn(a0[r][0], binu1);
    hLDS[r * HD + u2] = __fadd_rn(a0[r][1], binu2);
  }

  // loop-invariant biases (identical values to per-step reload)
  float biasg[NU][4];
#pragma unroll
  for (int g = 0; g < 4; ++g) {
    biasg[0][g] = __fadd_rn(b_ih[g * HD + u],  b_hh[g * HD + u]);
    biasg[1][g] = __fadd_rn(b_ih[g * HD + u2], b_hh[g * HD + u2]);
  }
  const float boutv = b_out[v];

  float c[RB][NU];
#pragma unroll
  for (int r = 0; r < RB; ++r)
#pragma unroll
    for (int n = 0; n < NU; ++n) c[r][n] = 0.0f;

  __syncthreads();                     // h0 visible

  for (int t = 0; t < NSTEP; ++t) {
    // ---- fused GEMM over h(t-1): gates(t) for 8 rows x 2 units + logits(t-1)
    float acc[RB][4][NU];
    float la[4];
#pragma unroll
    for (int rr = 0; rr < RB; ++rr)
#pragma unroll
      for (int g = 0; g < 4; ++g)
#pragma unroll
        for (int n = 0; n < NU; ++n) acc[rr][g][n] = 0.0f;
#pragma unroll
    for (int j = 0; j < 4; ++j) la[j] = 0.0f;

    for (int kb = 0; kb < HD / 4; ++kb) {
      const fv4* wp1 = Wg4 + ((size_t)kb << 11) + (u << 2);   // 4 contiguous fv4
      const fv4* wp2 = Wg4 + ((size_t)kb << 11) + (u2 << 2);
      fv4 wv1[4], wv2[4];
#pragma unroll
      for (int g = 0; g < 4; ++g) { wv1[g] = wp1[g]; wv2[g] = wp2[g]; }
      fv4 wvo = Wout4[kb * 128 + v];
#pragma unroll
      for (int rr = 0; rr < RB; ++rr) {
        const int r = (rr + rqs) & (RB - 1);   // wave-uniform: broadcast read
        fv4 hv = hLDS4[r * 128 + kb];
#pragma unroll
        for (int g = 0; g < 4; ++g) {
          acc[rr][g][0] = __builtin_fmaf(wv1[g][0], hv[0], acc[rr][g][0]);
          acc[rr][g][0] = __builtin_fmaf(wv1[g][1], hv[1], acc[rr][g][0]);
          acc[rr][g][0] = __builtin_fmaf(wv1[g][2], hv[2], acc[rr][g][0]);
          acc[rr][g][0] = __builtin_fmaf(wv1[g][3], hv[3], acc[rr][g][0]);
          acc[rr][g][1] = __builtin_fmaf(wv2[g][0], hv[0], acc[rr][g][1]);
          acc[rr][g][1] = __builtin_fmaf(wv2[g][1], hv[1], acc[rr][g][1]);
          acc[rr][g][1] = __builtin_fmaf(wv2[g][2], hv[2], acc[rr][g][1]);
          acc[rr][g][1] = __builtin_fmaf(wv2[g][3], hv[3], acc[rr][g][1]);
        }
        if (rr < 4) {  // compile-time: row rqs+rr carries this thread's logits
          la[rr] = __builtin_fmaf(wvo[0], hv[0], la[rr]);
          la[rr] = __builtin_fmaf(wvo[1], hv[1], la[rr]);
          la[rr] = __builtin_fmaf(wvo[2], hv[2], la[rr]);
          la[rr] = __builtin_fmaf(wvo[3], hv[3], la[rr]);
        }
      }
    }

    // ---- publish logits(t-1) + wave-parallel exact argmax
    if (t > 0) {
#pragma unroll
      for (int j = 0; j < 4; ++j) {
        float val = __fadd_rn(la[j], boutv);
        out[(size_t)((row0 + rqs + j) * NSTEP + (t - 1)) * VOC + v] = val;
        float mv = val;
        int   mi = v;
#pragma unroll
        for (int m = 1; m < 64; m <<= 1) {
          float ov = __shfl_xor(mv, m);
          int   oi = __shfl_xor(mi, m);
          bool take = (ov > mv) || (ov == mv && oi < mi);  // first-max
          mv = take ? ov : mv;
          mi = take ? oi : mi;
        }
        if ((tid & 63) == 0)
          cand[rqs + j][wpar] = make_float2(mv, __int_as_float(mi));
      }
    }
    __syncthreads();   // (A): cand visible; all GEMM reads of h(t-1) done

    // ---- elementwise (verbatim numerics), rows in rotated order
#pragma unroll
    for (int rr = 0; rr < RB; ++rr) {
      const int r = (rr + rqs) & (RB - 1);
      int ix = 0;
      if (t > 0) {
        float2 c0 = cand[r][0], c1 = cand[r][1];
        // wave1 indices are all >= 64 > wave0's, so strict > keeps first-max
        ix = (c1.x > c0.x) ? __float_as_int(c1.y) : __float_as_int(c0.y);
      }
      fv4 t41 = *(const fv4*)&Wih[((size_t)ix << 11) + (u << 2)];
      fv4 t42 = *(const fv4*)&Wih[((size_t)ix << 11) + (u2 << 2)];
#pragma unroll
      for (int n = 0; n < NU; ++n) {
        fv4 t4 = (n == 0) ? t41 : t42;
        float ga[4];
#pragma unroll
        for (int g = 0; g < 4; ++g)
          ga[g] = __fadd_rn(__fadd_rn(t4[g], acc[rr][g][n]), biasg[n][g]);
        float ig = sig_np(ga[0]);
        float fg = sig_np(ga[1]);
        float gg = tanh_np(ga[2]);
        float og = sig_np(ga[3]);
        float cn = __fadd_rn(__fmul_rn(fg, c[rr][n]), __fmul_rn(ig, gg));
        c[rr][n] = cn;
        hLDS[r * HD + (n == 0 ? u : u2)] = __fmul_rn(og, tanh_np(cn));
      }
    }
    __syncthreads();   // (B): h(t) visible for next GEMM
  }

  // ---- epilogue: logits(19) (identical chain order to the fused path)
  {
    float la2[4];
#pragma unroll
    for (int j = 0; j < 4; ++j) la2[j] = 0.0f;
    for (int kb = 0; kb < HD / 4; ++kb) {
      fv4 wvo = Wout4[kb * 128 + v];
#pragma unroll
      for (int j = 0; j < 4; ++j) {
        fv4 hv = hLDS4[(rqs + j) * 128 + kb];
        la2[j] = __builtin_fmaf(wvo[0], hv[0], la2[j]);
        la2[j] = __builtin_fmaf(wvo[1], hv[1], la2[j]);
        la2[j] = __builtin_fmaf(wvo[2], hv[2], la2[j]);
        la2[j] = __builtin_fmaf(wvo[3], hv[3], la2[j]);
      }
    }
#pragma unroll
    for (int j = 0; j < 4; ++j)
      out[(size_t)((row0 + rqs + j) * NSTEP + (NSTEP - 1)) * VOC + v] =
          __fadd_rn(la2[j], boutv);
  }
}

extern "C" void kernel_launch(void* const* d_in, const int* in_sizes, int n_in,
                              void* d_out, int out_size, void* d_ws, size_t ws_size,
                              hipStream_t stream) {
  const float* quant = (const float*)d_in[0];
  const float* w_in  = (const float*)d_in[1];
  const float* b_in  = (const float*)d_in[2];
  const float* w_ih  = (const float*)d_in[3];
  const float* w_hh  = (const float*)d_in[4];
  const float* b_ih  = (const float*)d_in[5];
  const float* b_hh  = (const float*)d_in[6];
  const float* w_out = (const float*)d_in[7];
  const float* b_out = (const float*)d_in[8];
  float* out = (float*)d_out;
  float* ws  = (float*)d_ws;

  repack_kernel<<<4096, 256, 0, stream>>>(w_in, w_ih, w_hh, w_out, ws);
  decoder_fast<<<8192 / RB, TPB, 0, stream>>>(quant, b_in, b_ih, b_hh, b_out,
                                              ws, out);
}

// Round 9
// 5988.261 us; speedup vs baseline: 1.0895x; 1.0895x over previous
//
#include <hip/hip_runtime.h>
#include <math.h>

typedef float fv4 __attribute__((ext_vector_type(4)));

#define NSTEP 20
#define HD 512
#define QD 256
#define VOC 128
#define RB 16         // rows per block (verified sweet spot)
#define TPB 512
#define CREG 2        // c kept in registers for loop positions RB-2, RB-1
#define CLDSROWS (RB - CREG)

// ws layout (float offsets)
#define WG_OFF   0          // [kb=128][u=512][g=4][ki=4] = 1048576 floats (4 MB)
#define WIH_OFF  1048576    // [x=128][u=512][g=4]        = 262144
#define WIN_OFF  1310720    // [kb=64][u=512][ki=4]       = 131072
#define WOUT_OFF 1441792    // [kb=128][v=128][ki=4]      = 65536

// numpy-style f32 elementwise ops (verbatim from the passing round-5 kernel).
__device__ __forceinline__ float sig_np(float x) {
  float t = (float)exp(-(double)x);              // corr-rounded f32 exp
  return __fdiv_rn(1.0f, __fadd_rn(1.0f, t));
}
__device__ __forceinline__ float tanh_np(float x) {
  return (float)tanh((double)x);
}

// Repack weights into lane-contiguous layouts (pure data movement; the values
// feeding each FMA chain are unchanged, so the trajectory stays bit-identical).
// Wg[kb][u][g][ki]: a thread's 4 gate-vectors are 64 B contiguous (1 addr calc,
// offsets folded). Wih[x][u][g]: per-row gate gather is a single dwordx4.
// (Both layouts ran bit-identical in R3/R4: absmax 0.00390625.)
__global__ void repack_kernel(const float* __restrict__ w_in,
                              const float* __restrict__ w_ih,
                              const float* __restrict__ w_hh,
                              const float* __restrict__ w_out,
                              float* __restrict__ ws) {
  int t = blockIdx.x * blockDim.x + threadIdx.x;
  {
    // Wg[kb][u][g][ki] = w_hh[(g*512+u)*512 + kb*4+ki]
    int ki = t & 3, g = (t >> 2) & 3, u = (t >> 4) & 511, kb = t >> 13;
    ws[WG_OFF + t] = w_hh[(size_t)(g * HD + u) * HD + kb * 4 + ki];
  }
  if (t < 262144) {
    // Wih[x][u][g] = w_ih[(g*512+u)*128 + x]
    int g = t & 3, u = (t >> 2) & 511, x = t >> 11;
    ws[WIH_OFF + t] = w_ih[(size_t)(g * HD + u) * VOC + x];
  }
  if (t < 131072) {
    // Win[kb][u][ki] = w_in[u*256 + kb*4+ki]
    int ki = t & 3, u = (t >> 2) & 511, kb = t >> 11;
    ws[WIN_OFF + t] = w_in[(size_t)u * QD + kb * 4 + ki];
  }
  if (t < 65536) {
    // Wout[kb][v][ki] = w_out[v*512 + kb*4+ki]
    int ki = t & 3, v = (t >> 2) & 127, kb = t >> 9;
    ws[WOUT_OFF + t] = w_out[(size_t)v * HD + kb * 4 + ki];
  }
}

// Persistent LSTM decoder; thread u owns hidden unit u for RB rows.
// R9 = the verified R1 structure (RB=16, TPB=512, fused logits GEMM,
// butterfly argmax, 2 barriers/step, (512,2) bounds) + ONLY the three
// bit-identical improvements validated in R3/R4 but masked there by spills:
//  (a) contiguous Wg loads (wp[0..3], offsets folded into one address),
//  (b) single-dwordx4 Wih gather in the elementwise phase,
//  (c) biasg/boutv hoisted out of the step loop.
// No explicit prefetch arrays, no async staging (R3/R4/R8 lessons).
// Every per-accumulator FMA chain is kb-ascending / ki-innermost with the
// same __fadd_rn associations => trajectory bit-identical.
__global__ __launch_bounds__(TPB, 2)
void decoder_fast(const float* __restrict__ quant,
                  const float* __restrict__ b_in,
                  const float* __restrict__ b_ih,
                  const float* __restrict__ b_hh,
                  const float* __restrict__ b_out,
                  const float* __restrict__ ws,
                  float* __restrict__ out) {
  __shared__ __align__(16) float hLDS[RB * HD];        // 32 KB: quant (prologue), then h
  __shared__ __align__(16) float cLDS[CLDSROWS * HD];  // 28 KB: c, loop positions 0..13
  __shared__ float2 cand[RB][2];                       // 256 B: per-row wave-pair argmax

  const int tid  = threadIdx.x;            // hidden unit 0..511
  const int row0 = blockIdx.x * RB;
  const int v    = tid & (VOC - 1);        // logit class owned by this thread
  const int rqs  = (tid >> 7) << 2;        // first logit row of this 128-thread group
  const int wpar = (tid >> 6) & 1;         // wave parity within the group

  const fv4* Wg4   = (const fv4*)(ws + WG_OFF);
  const float* Wih = ws + WIH_OFF;
  const fv4* Win4  = (const fv4*)(ws + WIN_OFF);
  const fv4* Wout4 = (const fv4*)(ws + WOUT_OFF);
  const fv4* hLDS4 = (const fv4*)hLDS;

  // ---- stage quant rows into hLDS (RB*QD = 4096 floats = 1024 fv4), coalesced
  {
    const fv4* src = (const fv4*)(quant + (size_t)row0 * QD);
    fv4* dst = (fv4*)hLDS;
    dst[tid]       = src[tid];
    dst[tid + TPB] = src[tid + TPB];
  }
  __syncthreads();

  // ---- h0 = quant @ w_in.T + b_in, into registers (exact chains)
  float a0[RB];
  {
    const fv4* q4 = (const fv4*)hLDS;
#pragma unroll
    for (int r = 0; r < RB; ++r) a0[r] = 0.0f;
    for (int kb = 0; kb < QD / 4; ++kb) {
      fv4 w = Win4[kb * 512 + tid];
#pragma unroll
      for (int r = 0; r < RB; ++r) {
        fv4 qv = q4[r * 64 + kb];
        a0[r] = __builtin_fmaf(w[0], qv[0], a0[r]);
        a0[r] = __builtin_fmaf(w[1], qv[1], a0[r]);
        a0[r] = __builtin_fmaf(w[2], qv[2], a0[r]);
        a0[r] = __builtin_fmaf(w[3], qv[3], a0[r]);
      }
    }
  }
  const float binu = b_in[tid];
  __syncthreads();                     // all quant reads done
#pragma unroll
  for (int r = 0; r < RB; ++r) hLDS[r * HD + tid] = __fadd_rn(a0[r], binu);

  // loop-invariant biases (identical values to per-step reload)
  float biasg[4];
#pragma unroll
  for (int g = 0; g < 4; ++g)
    biasg[g] = __fadd_rn(b_ih[g * HD + tid], b_hh[g * HD + tid]);
  const float boutv = b_out[v];

  float cR0 = 0.0f, cR1 = 0.0f;        // c for loop positions RB-2, RB-1

  __syncthreads();                     // h0 visible

  for (int t = 0; t < NSTEP; ++t) {
    // ---- fused GEMM over h(t-1): gates(t) for all 16 rows + logits(t-1)
    // acc[rr] accumulates row (rr + rqs) & 15; la[j] is row rqs+j (pos rr=j).
    float acc[RB][4];
    float la[4];
#pragma unroll
    for (int rr = 0; rr < RB; ++rr)
#pragma unroll
      for (int g = 0; g < 4; ++g) acc[rr][g] = 0.0f;
#pragma unroll
    for (int j = 0; j < 4; ++j) la[j] = 0.0f;

    for (int kb = 0; kb < HD / 4; ++kb) {
      const fv4* wp = Wg4 + ((size_t)kb << 11) + (tid << 2);  // 4 contiguous fv4
      fv4 wv[4];
#pragma unroll
      for (int g = 0; g < 4; ++g) wv[g] = wp[g];
      fv4 wvo = Wout4[kb * 128 + v];
#pragma unroll
      for (int rr = 0; rr < RB; ++rr) {
        const int r = (rr + rqs) & (RB - 1);   // wave-uniform: broadcast read
        fv4 hv = hLDS4[r * 128 + kb];
#pragma unroll
        for (int g = 0; g < 4; ++g) {
          acc[rr][g] = __builtin_fmaf(wv[g][0], hv[0], acc[rr][g]);
          acc[rr][g] = __builtin_fmaf(wv[g][1], hv[1], acc[rr][g]);
          acc[rr][g] = __builtin_fmaf(wv[g][2], hv[2], acc[rr][g]);
          acc[rr][g] = __builtin_fmaf(wv[g][3], hv[3], acc[rr][g]);
        }
        if (rr < 4) {  // compile-time: row rqs+rr carries this thread's logits
          la[rr] = __builtin_fmaf(wvo[0], hv[0], la[rr]);
          la[rr] = __builtin_fmaf(wvo[1], hv[1], la[rr]);
          la[rr] = __builtin_fmaf(wvo[2], hv[2], la[rr]);
          la[rr] = __builtin_fmaf(wvo[3], hv[3], la[rr]);
        }
      }
    }

    // ---- publish logits(t-1) + wave-parallel exact argmax
    if (t > 0) {
#pragma unroll
      for (int j = 0; j < 4; ++j) {
        float val = __fadd_rn(la[j], boutv);
        out[(size_t)((row0 + rqs + j) * NSTEP + (t - 1)) * VOC + v] = val;
        float mv = val;
        int   mi = v;
#pragma unroll
        for (int m = 1; m < 64; m <<= 1) {
          float ov = __shfl_xor(mv, m);
          int   oi = __shfl_xor(mi, m);
          bool take = (ov > mv) || (ov == mv && oi < mi);  // first-max
          mv = take ? ov : mv;
          mi = take ? oi : mi;
        }
        if ((tid & 63) == 0)
          cand[rqs + j][wpar] = make_float2(mv, __int_as_float(mi));
      }
    }
    __syncthreads();   // (A): cand visible; all GEMM reads of h(t-1) done

    // ---- elementwise (verbatim numerics), rows in rotated order
#pragma unroll
    for (int rr = 0; rr < RB; ++rr) {
      const int r = (rr + rqs) & (RB - 1);
      int ix = 0;
      if (t > 0) {
        float2 c0 = cand[r][0], c1 = cand[r][1];
        // wave1 indices are all >= 64 > wave0's, so strict > keeps first-max
        ix = (c1.x > c0.x) ? __float_as_int(c1.y) : __float_as_int(c0.y);
      }
      // one dwordx4: Wih[x=ix][u=tid][g=0..3] (same values as 4 strided loads)
      fv4 t4 = *(const fv4*)&Wih[((size_t)ix << 11) + (tid << 2)];
      float ga[4];
#pragma unroll
      for (int g = 0; g < 4; ++g)
        ga[g] = __fadd_rn(__fadd_rn(t4[g], acc[rr][g]), biasg[g]);
      float ig = sig_np(ga[0]);
      float fg = sig_np(ga[1]);
      float gg = tanh_np(ga[2]);
      float og = sig_np(ga[3]);
      float cold;
      if (rr == RB - 2)      cold = cR0;
      else if (rr == RB - 1) cold = cR1;
      else                   cold = cLDS[rr * HD + tid];
      if (t == 0) cold = 0.0f;
      float cn = __fadd_rn(__fmul_rn(fg, cold), __fmul_rn(ig, gg));
      if (rr == RB - 2)      cR0 = cn;
      else if (rr == RB - 1) cR1 = cn;
      else                   cLDS[rr * HD + tid] = cn;
      hLDS[r * HD + tid] = __fmul_rn(og, tanh_np(cn));
    }
    __syncthreads();   // (B): h(t) visible for next GEMM
  }

  // ---- epilogue: logits(19) (identical chain order to the fused path)
  {
    float la2[4];
#pragma unroll
    for (int j = 0; j < 4; ++j) la2[j] = 0.0f;
    for (int kb = 0; kb < HD / 4; ++kb) {
      fv4 wvo = Wout4[kb * 128 + v];
#pragma unroll
      for (int j = 0; j < 4; ++j) {
        fv4 hv = hLDS4[(rqs + j) * 128 + kb];
        la2[j] = __builtin_fmaf(wvo[0], hv[0], la2[j]);
        la2[j] = __builtin_fmaf(wvo[1], hv[1], la2[j]);
        la2[j] = __builtin_fmaf(wvo[2], hv[2], la2[j]);
        la2[j] = __builtin_fmaf(wvo[3], hv[3], la2[j]);
      }
    }
#pragma unroll
    for (int j = 0; j < 4; ++j)
      out[(size_t)((row0 + rqs + j) * NSTEP + (NSTEP - 1)) * VOC + v] =
          __fadd_rn(la2[j], boutv);
  }
}

extern "C" void kernel_launch(void* const* d_in, const int* in_sizes, int n_in,
                              void* d_out, int out_size, void* d_ws, size_t ws_size,
                              hipStream_t stream) {
  const float* quant = (const float*)d_in[0];
  const float* w_in  = (const float*)d_in[1];
  const float* b_in  = (const float*)d_in[2];
  const float* w_ih  = (const float*)d_in[3];
  const float* w_hh  = (const float*)d_in[4];
  const float* b_ih  = (const float*)d_in[5];
  const float* b_hh  = (const float*)d_in[6];
  const float* w_out = (const float*)d_in[7];
  const float* b_out = (const float*)d_in[8];
  float* out = (float*)d_out;
  float* ws  = (float*)d_ws;

  repack_kernel<<<4096, 256, 0, stream>>>(w_in, w_ih, w_hh, w_out, ws);
  decoder_fast<<<8192 / RB, TPB, 0, stream>>>(quant, b_in, b_ih, b_hh, b_out,
                                              ws, out);
}